// Round 5
// baseline (481.975 us; speedup 1.0000x reference)
//
#include <hip/hip_runtime.h>
#include <hip/hip_bf16.h>
#include <math.h>

// ---------------- problem constants ----------------
#define B_ROWS 1024
#define EMB    512
#define NCLS   100000
#define SCALE_ 64.0f
// margin = 0.5
#define COS_M 0.8775825618903728f
#define SIN_M 0.479425538604203f
#define TH_C  (-0.8775825618903728f)
#define MM_C  0.2397127693021015f

// ---------------- fallback GEMM tiling (128^2) ----------------
#define BM 128
#define BN 128
#define BK 32
#define NTILES 782   // ceil(100000/128)
#define KCHUNKS 16   // 512/32

// ---------------- fast GEMM tiling (256^2, BK=64, 8 waves, phase-pipelined) ------
#define NT2   391            // ceil(100000/256)
#define GRID2 1564           // 391 ytiles * 4 xtiles

typedef __attribute__((ext_vector_type(8))) short bf16x8;   // 8 bf16 = 4 VGPRs
typedef __attribute__((ext_vector_type(4))) short s16x4;
typedef __attribute__((ext_vector_type(4))) float f32x4;

typedef __attribute__((address_space(1))) const unsigned int GLP;
typedef __attribute__((address_space(3))) unsigned int LDP;

__device__ __forceinline__ float bf2f(short u) {
  unsigned int x = ((unsigned int)(unsigned short)u) << 16;
  return __builtin_bit_cast(float, x);
}
__device__ __forceinline__ short f2bf(float f) {   // RNE fp32 -> bf16
  unsigned int u = __builtin_bit_cast(unsigned int, f);
  u += 0x7FFF + ((u >> 16) & 1);
  return (short)(u >> 16);
}

// async global->LDS, 16B/lane; LDS dest = wave-uniform base, lane i lands at base + i*16
__device__ __forceinline__ void load16(const void* g, void* l) {
  __builtin_amdgcn_global_load_lds((GLP*)g, (LDP*)l, 16, 0, 0);
}

#define MFMA16 __builtin_amdgcn_mfma_f32_16x16x32_bf16
#define WAITLG do { asm volatile("s_waitcnt lgkmcnt(0)" ::: "memory"); \
                    __builtin_amdgcn_sched_barrier(0); } while (0)

// ---------------- setup: zero accums, detect label width AND input dtype ----------------
__global__ void setup_kernel(const void* __restrict__ emb, const int* __restrict__ labels,
                             float* __restrict__ row_sum, float* __restrict__ accum,
                             int* __restrict__ flag, int* __restrict__ dflag) {
  const int t = threadIdx.x;           // 512 threads
  row_sum[t] = 0.f;
  row_sum[t + 512] = 0.f;
  if (t == 0) *accum = 0.f;

  if (t < 64) {
    bf16x8 v = *(const bf16x8*)((const short*)emb + t * 8);
    float s = 0.f;
    #pragma unroll
    for (int j = 0; j < 8; ++j) { float f = bf2f(v[j]); s += f * f; }
    #pragma unroll
    for (int off = 1; off < 64; off <<= 1) s += __shfl_xor(s, off);
    if (t == 0) *dflag = (s < 1e8f) ? 1 : 0;       // NaN/inf compare false -> fp32
  }

  int v = labels[2 * t + 1];
  #pragma unroll
  for (int off = 1; off < 64; off <<= 1) v |= __shfl_xor(v, off);
  __shared__ int red[8];
  if ((t & 63) == 0) red[t >> 6] = v;
  __syncthreads();
  if (t == 0) {
    int o = 0;
    #pragma unroll
    for (int i = 0; i < 8; ++i) o |= red[i];
    *flag = (o == 0) ? 1 : 0;          // 1 => int64 labels (read low word at 2*r)
  }
}

// ---------------- inverse L2 norms + (optional) normalized-bf16 write-back ----------------
// v2 layout (proven best): 16 lanes/row, 128 B loads/thread, 4-round shfl reduce.
__global__ __launch_bounds__(256) void normconv_kernel(
    const void* __restrict__ emb, const void* __restrict__ wgt,
    const int* __restrict__ dflag,
    float* __restrict__ inv_e, float* __restrict__ inv_w,
    short* __restrict__ An, short* __restrict__ Wn, const int do_conv) {
  const int sub  = threadIdx.x & 15;       // lane within row-group
  const int rloc = threadIdx.x >> 4;       // 0..15 rows per block
  const int row  = blockIdx.x * 16 + rloc;
  int r;
  const void* base;
  float* dst;
  short* out;
  if (row < B_ROWS) { r = row; base = emb; dst = inv_e + row; out = An + (size_t)row * EMB; }
  else {
    r = row - B_ROWS;
    if (r >= NCLS) return;
    base = wgt; dst = inv_w + r; out = Wn + (size_t)r * EMB;
  }
  const int isbf16 = *dflag;
  float f[32];
  if (isbf16) {
    const short* p = (const short*)base + (size_t)r * EMB;
    #pragma unroll
    for (int j = 0; j < 4; ++j) {
      bf16x8 v = *(const bf16x8*)(p + j * 128 + sub * 8);
      #pragma unroll
      for (int t = 0; t < 8; ++t) f[j * 8 + t] = bf2f(v[t]);
    }
  } else {
    const float* p = (const float*)base + (size_t)r * EMB;
    #pragma unroll
    for (int j = 0; j < 8; ++j) {
      f32x4 v = *(const f32x4*)(p + j * 64 + sub * 4);
      #pragma unroll
      for (int t = 0; t < 4; ++t) f[j * 4 + t] = v[t];
    }
  }
  float s = 0.f;
  #pragma unroll
  for (int j = 0; j < 32; ++j) s += f[j] * f[j];
  #pragma unroll
  for (int off = 1; off < 16; off <<= 1) s += __shfl_xor(s, off);
  const float inv = 1.f / fmaxf(sqrtf(s), 1e-12f);
  if (sub == 0) *dst = inv;
  if (do_conv) {
    if (isbf16) {
      #pragma unroll
      for (int j = 0; j < 4; ++j) {
        bf16x8 o;
        #pragma unroll
        for (int t = 0; t < 8; ++t) o[t] = f2bf(f[j * 8 + t] * inv);
        *(bf16x8*)(out + j * 128 + sub * 8) = o;
      }
    } else {
      #pragma unroll
      for (int j = 0; j < 8; ++j) {
        s16x4 o;
        #pragma unroll
        for (int t = 0; t < 4; ++t) o[t] = f2bf(f[j * 4 + t] * inv);
        *(s16x4*)(out + j * 64 + sub * 4) = o;
      }
    }
  }
}

// ---------------- FAST PATH: 256^2 BK=64 phase-pipelined NT-GEMM ----------------
// 8 waves (2M x 4N). 4 gray-code quadrant phases per K-tile; counted vmcnt(2);
// raw s_barrier (no vmcnt drain); setprio around MFMA clusters; XOR slot-swizzle
// (slot ^= row&7) via pre-swizzled global source (verified in round 3).
__global__ __launch_bounds__(512, 2) void arc_gemm_fast(
    const short* __restrict__ A, const short* __restrict__ W,
    const int* __restrict__ labels, const int* __restrict__ flag,
    float* __restrict__ row_sum, float* __restrict__ lablogit) {
  // bijective XCD map (nwg=1564, q=195, r=4): wgid/4 = ytile, wgid%4 = xtile
  const int bid = blockIdx.x;
  const int k   = bid & 7;
  const int jj  = bid >> 3;
  const int wgid = (k < 4 ? k * 196 : 4 * 196 + (k - 4) * 195) + jj;
  const int ytile = wgid >> 2;
  const int xtile = wgid & 3;
  if (ytile >= NT2) return;

  // LDS: 2 bufs x (A 32KB | B 32KB) = 128 KB, + labels 1KB + partial sums 4KB
  __shared__ __align__(16) char L[131072 + 1024 + 4096];
  int*   shl = (int*)(L + 131072);
  float* shs = (float*)(L + 131072 + 1024);

  const int tid  = threadIdx.x;
  const int wave = tid >> 6;
  const int lane = tid & 63;
  const int wm   = wave >> 2;        // 0..1  (M half: 128 rows)
  const int wn   = wave & 3;         // 0..3  (N quarter: 64 cols)
  const int lr16 = lane & 15;
  const int lkg  = lane >> 4;        // 0..3
  const int mBase = xtile * 256;
  const int nBase = ytile * 256;

  const char* Ab = (const char*)A;   // bf16 row stride 1024 B
  const char* Wb = (const char*)W;

  // staging thread coords: row-in-64 = tid>>3, slot = tid&7 (dest linear);
  // source slot pre-swizzled: sslot = (tid&7) ^ ((tid>>3)&7)   [row&7 == (tid>>3)&7]
  const int sslot = (tid & 7) ^ ((tid >> 3) & 7);

  auto stage_one = [&](int s, int ii) {   // tile s (k-bytes s*128), load ii in 0..7
    const int pp = s & 1;
    const int rloc = (ii & 3) * 64 + (tid >> 3);
    const char* src;
    if (ii < 4) {
      src = Ab + (size_t)(mBase + rloc) * 1024 + (size_t)s * 128 + sslot * 16;
    } else {
      int br = nBase + rloc;
      if (br >= NCLS) br = NCLS - 1;           // clamp; masked in epilogue
      src = Wb + (size_t)br * 1024 + (size_t)s * 128 + sslot * 16;
    }
    load16(src, L + pp * 65536 + ii * 8192 + wave * 1024);
  };
  auto stage_pair = [&](int s, int l) {       // in-loop: only tiles 2..7
    if ((unsigned)(s - 2) > 5u) return;
    stage_one(s, 2 * l);
    stage_one(s, 2 * l + 1);
  };

  f32x4 zero = {0.f, 0.f, 0.f, 0.f};
  f32x4 acc[8][4];
  #pragma unroll
  for (int i = 0; i < 8; ++i)
    #pragma unroll
    for (int j2 = 0; j2 < 4; ++j2) acc[i][j2] = zero;

  // read-side swizzled slot indices (constant per lane): logical slot sigma in 0..7
  const int slA  = lkg ^ (lr16 & 7);          // ks=0
  const int slB  = slA ^ 4;                   // ks=1

  // ---- prologue: fully stage tiles 0 and 1 ----
  #pragma unroll
  for (int ii = 0; ii < 8; ++ii) stage_one(0, ii);
  #pragma unroll
  for (int ii = 0; ii < 8; ++ii) stage_one(1, ii);
  asm volatile("s_waitcnt vmcnt(8)" ::: "memory");   // tile 0 landed (tile 1 may fly)
  __builtin_amdgcn_s_barrier();

  bf16x8 af0[4], af1[4];        // current mi-half, ks0/ks1
  bf16x8 b01[2][2], b23[2][2];  // [ks][ni&1] for ni 0-1 and 2-3 (kept whole tile)

  for (int t = 0; t < 8; ++t) {
    const int p = t & 1;
    const short* AL = (const short*)(L + p * 65536);
    const short* BL = (const short*)(L + p * 65536 + 32768);

    // ---------- q0: read afL(8) + b01(4); stage (t+1, l1); MFMA mi0-3 x ni0-1 ----------
    #pragma unroll
    for (int mi = 0; mi < 4; ++mi) {
      const int row = wm * 128 + mi * 16 + lr16;
      af0[mi] = *(const bf16x8*)(AL + row * 64 + slA * 8);
      af1[mi] = *(const bf16x8*)(AL + row * 64 + slB * 8);
    }
    #pragma unroll
    for (int ni = 0; ni < 2; ++ni) {
      const int row = wn * 64 + ni * 16 + lr16;
      b01[0][ni] = *(const bf16x8*)(BL + row * 64 + slA * 8);
      b01[1][ni] = *(const bf16x8*)(BL + row * 64 + slB * 8);
    }
    stage_pair(t + 1, 1);
    __builtin_amdgcn_s_barrier();
    __builtin_amdgcn_s_setprio(1);
    #pragma unroll
    for (int mi = 0; mi < 4; ++mi)
      #pragma unroll
      for (int ni = 0; ni < 2; ++ni) {
        acc[mi][ni] = MFMA16(af0[mi], b01[0][ni], acc[mi][ni], 0, 0, 0);
        acc[mi][ni] = MFMA16(af1[mi], b01[1][ni], acc[mi][ni], 0, 0, 0);
      }
    __builtin_amdgcn_s_setprio(0);
    WAITLG;
    __builtin_amdgcn_s_barrier();

    // ---------- q1: read b23(4); stage (t+1, l2); MFMA mi0-3 x ni2-3 ----------
    #pragma unroll
    for (int ni = 0; ni < 2; ++ni) {
      const int row = wn * 64 + (ni + 2) * 16 + lr16;
      b23[0][ni] = *(const bf16x8*)(BL + row * 64 + slA * 8);
      b23[1][ni] = *(const bf16x8*)(BL + row * 64 + slB * 8);
    }
    stage_pair(t + 1, 2);
    __builtin_amdgcn_s_barrier();
    __builtin_amdgcn_s_setprio(1);
    #pragma unroll
    for (int mi = 0; mi < 4; ++mi)
      #pragma unroll
      for (int ni = 0; ni < 2; ++ni) {
        acc[mi][ni + 2] = MFMA16(af0[mi], b23[0][ni], acc[mi][ni + 2], 0, 0, 0);
        acc[mi][ni + 2] = MFMA16(af1[mi], b23[1][ni], acc[mi][ni + 2], 0, 0, 0);
      }
    __builtin_amdgcn_s_setprio(0);
    WAITLG;
    __builtin_amdgcn_s_barrier();

    // ---------- q2: read afR(8); stage (t+1, l3); MFMA mi4-7 x ni2-3 ----------
    #pragma unroll
    for (int mi = 0; mi < 4; ++mi) {
      const int row = wm * 128 + (mi + 4) * 16 + lr16;
      af0[mi] = *(const bf16x8*)(AL + row * 64 + slA * 8);
      af1[mi] = *(const bf16x8*)(AL + row * 64 + slB * 8);
    }
    stage_pair(t + 1, 3);
    __builtin_amdgcn_s_barrier();
    __builtin_amdgcn_s_setprio(1);
    #pragma unroll
    for (int mi = 0; mi < 4; ++mi)
      #pragma unroll
      for (int ni = 0; ni < 2; ++ni) {
        acc[mi + 4][ni + 2] = MFMA16(af0[mi], b23[0][ni], acc[mi + 4][ni + 2], 0, 0, 0);
        acc[mi + 4][ni + 2] = MFMA16(af1[mi], b23[1][ni], acc[mi + 4][ni + 2], 0, 0, 0);
      }
    __builtin_amdgcn_s_setprio(0);
    WAITLG;
    __builtin_amdgcn_s_barrier();

    // ---------- q3: no reads; stage (t+2, l0); MFMA mi4-7 x ni0-1; counted vmcnt ----------
    stage_pair(t + 2, 0);
    __builtin_amdgcn_s_barrier();
    __builtin_amdgcn_s_setprio(1);
    #pragma unroll
    for (int mi = 0; mi < 4; ++mi)
      #pragma unroll
      for (int ni = 0; ni < 2; ++ni) {
        acc[mi + 4][ni] = MFMA16(af0[mi], b01[0][ni], acc[mi + 4][ni], 0, 0, 0);
        acc[mi + 4][ni] = MFMA16(af1[mi], b01[1][ni], acc[mi + 4][ni], 0, 0, 0);
      }
    __builtin_amdgcn_s_setprio(0);
    WAITLG;
    // protect tile t+1's q0 reads: after its window, only (t+2,l0)'s 2 loads were issued
    if (t < 6)      asm volatile("s_waitcnt vmcnt(2)" ::: "memory");
    else if (t == 6) asm volatile("s_waitcnt vmcnt(0)" ::: "memory");
    __builtin_amdgcn_s_barrier();
  }

  // ---- epilogue (cos = accumulator directly; inputs pre-normalized) ----
  __syncthreads();
  if (tid < 256) {
    const int r = mBase + tid;
    const int f = *flag;
    shl[tid] = labels[f ? (size_t)(2 * r) : (size_t)r];
  }
  __syncthreads();

  #pragma unroll
  for (int mi = 0; mi < 8; ++mi) {
    #pragma unroll
    for (int reg = 0; reg < 4; ++reg) {
      const int lrow = wm * 128 + mi * 16 + lkg * 4 + reg;   // C/D: row=(lane>>4)*4+reg
      const int grow = mBase + lrow;
      const int lab = shl[lrow];
      float s = 0.f;
      #pragma unroll
      for (int ni = 0; ni < 4; ++ni) {
        const int gcol = nBase + wn * 64 + ni * 16 + lr16;   // C/D: col=lane&15
        if (gcol < NCLS) {
          const float cosv = acc[mi][ni][reg];
          float logit;
          if (gcol == lab) {
            const float sine = sqrtf(fmaxf(1.f - cosv * cosv, 0.f));
            float phi = cosv * COS_M - sine * SIN_M;
            phi = (cosv > TH_C) ? phi : (cosv - MM_C);
            logit = SCALE_ * phi;
            lablogit[grow] = logit;                          // unique writer grid-wide
          } else {
            logit = SCALE_ * cosv;
          }
          s += __expf(logit - SCALE_);                       // offset-64 softmax partial
        }
      }
      #pragma unroll
      for (int off = 1; off < 16; off <<= 1) s += __shfl_xor(s, off);
      if (lr16 == 0) shs[lrow * 4 + wn] = s;
    }
  }
  __syncthreads();
  if (tid < 256)
    atomicAdd(&row_sum[mBase + tid],
              shs[tid * 4] + shs[tid * 4 + 1] + shs[tid * 4 + 2] + shs[tid * 4 + 3]);
}

// ---------------- FALLBACK: fused NT-GEMM with in-loop dtype staging (128^2) ----------------
__global__ __launch_bounds__(256, 3) void arc_gemm(
    const void* __restrict__ A, const void* __restrict__ W,
    const float* __restrict__ inv_e, const float* __restrict__ inv_w,
    const int* __restrict__ labels, const int* __restrict__ flag,
    const int* __restrict__ dflag,
    float* __restrict__ row_sum, float* __restrict__ lablogit) {
  __shared__ short As[BM * BK];
  __shared__ short Bs[BN * BK];
  __shared__ int   sh_lab[BM];
  __shared__ float sh_sum[BM][2];

  const int tid  = threadIdx.x;
  const int wave = tid >> 6;
  const int lane = tid & 63;
  const int wy = wave >> 1;
  const int wx = wave & 1;
  const int lr = lane & 15;
  const int lk = lane >> 4;
  const int mBase = blockIdx.x * BM;
  const int nBase = blockIdx.y * BN;
  const int isbf16 = *dflag;

  const int srow  = lane >> 2;
  const int sbyte = (lane & 3) * 16;

  f32x4 zero = {0.f, 0.f, 0.f, 0.f};
  f32x4 acc[4][4];
  #pragma unroll
  for (int i = 0; i < 4; ++i)
    #pragma unroll
    for (int j = 0; j < 4; ++j) acc[i][j] = zero;

  const char*  Ab = (const char*)A;
  const char*  Wb = (const char*)W;
  const float* Af = (const float*)A;
  const float* Wf = (const float*)W;

  for (int kc = 0; kc < KCHUNKS; ++kc) {
    __syncthreads();
    if (isbf16) {
      const size_t koff = (size_t)kc * 64 + sbyte;
      #pragma unroll
      for (int it = 0; it < 2; ++it) {
        const int c = wave + it * 4;
        const int ar = mBase + c * 16 + srow;
        load16(Ab + (size_t)ar * 1024 + koff, (char*)As + (size_t)c * 1024);
        int br = nBase + c * 16 + srow;
        if (br >= NCLS) br = NCLS - 1;
        load16(Wb + (size_t)br * 1024 + koff, (char*)Bs + (size_t)c * 1024);
      }
    } else {
      #pragma unroll
      for (int p = 0; p < 2; ++p) {
        const int u   = p * 256 + tid;
        const int row = u >> 2;
        const int seg = u & 3;
        const float* ga = Af + ((size_t)(mBase + row) * EMB + kc * 32 + seg * 8);
        f32x4 x = *(const f32x4*)ga;
        f32x4 y = *(const f32x4*)(ga + 4);
        bf16x8 tpack;
        #pragma unroll
        for (int j = 0; j < 4; ++j) { tpack[j] = f2bf(x[j]); tpack[j + 4] = f2bf(y[j]); }
        *(bf16x8*)(As + row * BK + seg * 8) = tpack;
        int br = nBase + row;
        if (br >= NCLS) br = NCLS - 1;
        const float* gb = Wf + ((size_t)br * EMB + kc * 32 + seg * 8);
        x = *(const f32x4*)gb;
        y = *(const f32x4*)(gb + 4);
        #pragma unroll
        for (int j = 0; j < 4; ++j) { tpack[j] = f2bf(x[j]); tpack[j + 4] = f2bf(y[j]); }
        *(bf16x8*)(Bs + row * BK + seg * 8) = tpack;
      }
    }
    __syncthreads();
    bf16x8 af[4], bfr[4];
    #pragma unroll
    for (int mi = 0; mi < 4; ++mi)
      af[mi] = *(const bf16x8*)(As + ((wy * 64 + mi * 16 + lr) * BK + lk * 8));
    #pragma unroll
    for (int ni = 0; ni < 4; ++ni)
      bfr[ni] = *(const bf16x8*)(Bs + ((wx * 64 + ni * 16 + lr) * BK + lk * 8));
    #pragma unroll
    for (int mi = 0; mi < 4; ++mi)
      #pragma unroll
      for (int ni = 0; ni < 4; ++ni)
        acc[mi][ni] = MFMA16(af[mi], bfr[ni], acc[mi][ni], 0, 0, 0);
  }

  __syncthreads();
  if (tid < BM) {
    const int r = mBase + tid;
    const int f = *flag;
    sh_lab[tid] = labels[f ? (size_t)(2 * r) : (size_t)r];
  }
  __syncthreads();

  #pragma unroll
  for (int mi = 0; mi < 4; ++mi) {
    #pragma unroll
    for (int reg = 0; reg < 4; ++reg) {
      const int lrow = wy * 64 + mi * 16 + lk * 4 + reg;
      const int grow = mBase + lrow;
      const float ie = inv_e[grow];
      const int lab = sh_lab[lrow];
      float s = 0.f;
      #pragma unroll
      for (int ni = 0; ni < 4; ++ni) {
        const int gcol = nBase + wx * 64 + ni * 16 + lr;
        if (gcol < NCLS) {
          const float cosv = acc[mi][ni][reg] * ie * inv_w[gcol];
          float logit;
          if (gcol == lab) {
            const float sine = sqrtf(fmaxf(1.f - cosv * cosv, 0.f));
            float phi = cosv * COS_M - sine * SIN_M;
            phi = (cosv > TH_C) ? phi : (cosv - MM_C);
            logit = SCALE_ * phi;
            lablogit[grow] = logit;
          } else {
            logit = SCALE_ * cosv;
          }
          s += __expf(logit - SCALE_);
        }
      }
      #pragma unroll
      for (int off = 1; off < 16; off <<= 1) s += __shfl_xor(s, off);
      if (lr == 0) sh_sum[lrow][wx] = s;
    }
  }
  __syncthreads();
  if (tid < BM)
    atomicAdd(&row_sum[mBase + tid], sh_sum[tid][0] + sh_sum[tid][1]);
}

// ---------------- fused per-row loss -> mean (single block) ----------------
__global__ __launch_bounds__(512) void loss_kernel(const float* __restrict__ row_sum,
                                                   const float* __restrict__ lablogit,
                                                   float* __restrict__ out) {
  const int t = threadIdx.x;
  float loss = 0.f;
  #pragma unroll
  for (int i = 0; i < 2; ++i) {
    const int r = t + i * 512;
    loss += SCALE_ + logf(row_sum[r]) - lablogit[r];
  }
  #pragma unroll
  for (int off = 1; off < 64; off <<= 1) loss += __shfl_xor(loss, off);
  __shared__ float rs[8];
  if ((t & 63) == 0) rs[t >> 6] = loss;
  __syncthreads();
  if (t == 0) {
    float s = 0.f;
    #pragma unroll
    for (int i = 0; i < 8; ++i) s += rs[i];
    out[0] = s * (1.0f / 1024.0f);   // reference output is float32
  }
}

// ---------------- launch ----------------
extern "C" void kernel_launch(void* const* d_in, const int* in_sizes, int n_in,
                              void* d_out, int out_size, void* d_ws, size_t ws_size,
                              hipStream_t stream) {
  const void* emb   = d_in[0];          // [1024][512]  bf16 or fp32 (auto-detected)
  const void* wgt   = d_in[1];          // [100000][512]
  const int* labels = (const int*)d_in[2];   // int32 or int64 (auto-detected)
  float* out = (float*)d_out;

  const int NORM_BLOCKS = (B_ROWS + NCLS + 15) / 16;   // 16 rows/block

  // fast-path workspace: pre-normalized bf16 copies of W and A
  const size_t WN_SHORTS = (size_t)NCLS * EMB;        // 51,200,000
  const size_t AN_SHORTS = (size_t)B_ROWS * EMB;      // 524,288
  const size_t FAST_NEED = (WN_SHORTS + AN_SHORTS) * 2 + 103075u * 4;  // ~103.9 MB

  if (ws_size >= FAST_NEED) {
    short* Wn = (short*)d_ws;
    short* An = Wn + WN_SHORTS;
    float* tail     = (float*)(An + AN_SHORTS);
    float* inv_e    = tail;               // 1024 (fallback parity)
    float* inv_w    = tail + 1024;        // 100000
    float* lablogit = tail + 101024;      // 1024
    float* row_sum  = tail + 102048;      // 1024
    float* accum    = tail + 103072;      // 1
    int*   flag     = (int*)(tail + 103073);
    int*   dflag    = (int*)(tail + 103074);

    setup_kernel<<<1, 512, 0, stream>>>(emb, labels, row_sum, accum, flag, dflag);
    normconv_kernel<<<NORM_BLOCKS, 256, 0, stream>>>(
        emb, wgt, dflag, inv_e, inv_w, An, Wn, 1);
    arc_gemm_fast<<<GRID2, 512, 0, stream>>>(An, Wn, labels, flag, row_sum, lablogit);
    loss_kernel<<<1, 512, 0, stream>>>(row_sum, lablogit, out);
  } else {
    float* ws       = (float*)d_ws;
    float* inv_e    = ws;                 // 1024
    float* inv_w    = ws + 1024;          // 100000
    float* lablogit = ws + 101024;        // 1024
    float* row_sum  = ws + 102048;        // 1024
    float* accum    = ws + 103072;        // 1
    int*   flag     = (int*)(ws + 103073);
    int*   dflag    = (int*)(ws + 103074);

    setup_kernel<<<1, 512, 0, stream>>>(emb, labels, row_sum, accum, flag, dflag);
    normconv_kernel<<<NORM_BLOCKS, 256, 0, stream>>>(
        emb, wgt, dflag, inv_e, inv_w, (short*)inv_e, (short*)inv_e, 0);
    dim3 grid(8, NTILES);
    arc_gemm<<<grid, 256, 0, stream>>>(emb, wgt, inv_e, inv_w, labels, flag, dflag, row_sum, lablogit);
    loss_kernel<<<1, 512, 0, stream>>>(row_sum, lablogit, out);
  }
}

// Round 6
// 452.138 us; speedup vs baseline: 1.0660x; 1.0660x over previous
//
#include <hip/hip_runtime.h>
#include <hip/hip_bf16.h>
#include <math.h>

// ---------------- problem constants ----------------
#define B_ROWS 1024
#define EMB    512
#define NCLS   100000
#define SCALE_ 64.0f
// margin = 0.5
#define COS_M 0.8775825618903728f
#define SIN_M 0.479425538604203f
#define TH_C  (-0.8775825618903728f)
#define MM_C  0.2397127693021015f

// ---------------- GEMM tiling (128^2, proven) ----------------
#define BM 128
#define BN 128
#define BK 32
#define NTILES 782   // ceil(100000/128)
#define KCHUNKS 16   // 512/32

typedef __attribute__((ext_vector_type(8))) short bf16x8;   // 8 bf16 = 4 VGPRs
typedef __attribute__((ext_vector_type(4))) short s16x4;
typedef __attribute__((ext_vector_type(4))) float f32x4;

typedef __attribute__((address_space(1))) const unsigned int GLP;
typedef __attribute__((address_space(3))) unsigned int LDP;

__device__ __forceinline__ float bf2f(short u) {
  unsigned int x = ((unsigned int)(unsigned short)u) << 16;
  return __builtin_bit_cast(float, x);
}
__device__ __forceinline__ short f2bf(float f) {   // RNE fp32 -> bf16
  unsigned int u = __builtin_bit_cast(unsigned int, f);
  u += 0x7FFF + ((u >> 16) & 1);
  return (short)(u >> 16);
}

// async global->LDS, 16B/lane; LDS dest = wave-uniform base, lane i lands at base + i*16
__device__ __forceinline__ void load16(const void* g, void* l) {
  __builtin_amdgcn_global_load_lds((GLP*)g, (LDP*)l, 16, 0, 0);
}

#define MFMA16 __builtin_amdgcn_mfma_f32_16x16x32_bf16

// ---------------- setup: zero accums, detect label width AND input dtype ----------------
__global__ void setup_kernel(const void* __restrict__ emb, const int* __restrict__ labels,
                             float* __restrict__ row_sum, float* __restrict__ accum,
                             int* __restrict__ flag, int* __restrict__ dflag) {
  const int t = threadIdx.x;           // 512 threads
  row_sum[t] = 0.f;
  row_sum[t + 512] = 0.f;
  if (t == 0) *accum = 0.f;

  // ---- input dtype probe (wave 0): ssq of emb row 0 read AS bf16.
  if (t < 64) {
    bf16x8 v = *(const bf16x8*)((const short*)emb + t * 8);
    float s = 0.f;
    #pragma unroll
    for (int j = 0; j < 8; ++j) { float f = bf2f(v[j]); s += f * f; }
    #pragma unroll
    for (int off = 1; off < 64; off <<= 1) s += __shfl_xor(s, off);
    if (t == 0) *dflag = (s < 1e8f) ? 1 : 0;       // NaN/inf compare false -> fp32
  }

  // ---- label width probe: high words if int64 are all zero
  int v = labels[2 * t + 1];
  #pragma unroll
  for (int off = 1; off < 64; off <<= 1) v |= __shfl_xor(v, off);
  __shared__ int red[8];
  if ((t & 63) == 0) red[t >> 6] = v;
  __syncthreads();
  if (t == 0) {
    int o = 0;
    #pragma unroll
    for (int i = 0; i < 8; ++i) o |= red[i];
    *flag = (o == 0) ? 1 : 0;          // 1 => int64 labels (read low word at 2*r)
  }
}

// ---------------- inverse L2 norms + (optional) normalized-bf16 write-back ----------------
// v4: v2's per-instruction lane-contiguous addressing (16 lanes/row, 256B/instr),
// but TWO rows per thread (16 independent loads in flight) + non-temporal fp32
// reads (205 MB of fp32 W is dead after this pass; keep it out of L3 so the
// bf16 Wn stream stays resident for the gemm).
__global__ __launch_bounds__(256) void normconv_kernel(
    const void* __restrict__ emb, const void* __restrict__ wgt,
    const int* __restrict__ dflag,
    float* __restrict__ inv_e, float* __restrict__ inv_w,
    short* __restrict__ An, short* __restrict__ Wn, const int do_conv) {
  const int sub  = threadIdx.x & 15;       // lane within row-group
  const int rloc = threadIdx.x >> 4;       // 0..15
  const int isbf16 = *dflag;

  const float* pf[2];
  const short* pb[2];
  float* dst[2];
  short* out[2];
  bool   ok[2];
  #pragma unroll
  for (int h = 0; h < 2; ++h) {
    const int row = blockIdx.x * 32 + h * 16 + rloc;
    int r;
    const void* base;
    if (row < B_ROWS) {                      // blocks 0..31 are pure-emb (1024 = 32*32)
      r = row; base = emb; dst[h] = inv_e + row; out[h] = An + (size_t)row * EMB; ok[h] = true;
    } else {
      r = row - B_ROWS;
      ok[h] = (r < NCLS);
      if (r >= NCLS) r = NCLS - 1;           // clamp: safe load, stores guarded
      base = wgt; dst[h] = inv_w + r; out[h] = Wn + (size_t)r * EMB;
    }
    pf[h] = (const float*)base + (size_t)r * EMB;
    pb[h] = (const short*)base + (size_t)r * EMB;
  }

  if (!isbf16) {
    f32x4 v[2][8];
    #pragma unroll
    for (int j = 0; j < 8; ++j) {           // interleave the two rows' streams
      v[0][j] = __builtin_nontemporal_load((const f32x4*)(pf[0] + j * 64 + sub * 4));
      v[1][j] = __builtin_nontemporal_load((const f32x4*)(pf[1] + j * 64 + sub * 4));
    }
    #pragma unroll
    for (int h = 0; h < 2; ++h) {
      float s = 0.f;
      #pragma unroll
      for (int j = 0; j < 8; ++j)
        #pragma unroll
        for (int t = 0; t < 4; ++t) s += v[h][j][t] * v[h][j][t];
      #pragma unroll
      for (int off = 1; off < 16; off <<= 1) s += __shfl_xor(s, off);
      const float inv = 1.f / fmaxf(sqrtf(s), 1e-12f);
      if (ok[h]) {
        if (sub == 0) *dst[h] = inv;
        if (do_conv) {
          #pragma unroll
          for (int j = 0; j < 8; ++j) {
            s16x4 o;
            #pragma unroll
            for (int t = 0; t < 4; ++t) o[t] = f2bf(v[h][j][t] * inv);
            *(s16x4*)(out[h] + j * 64 + sub * 4) = o;
          }
        }
      }
    }
  } else {
    bf16x8 w[2][4];
    #pragma unroll
    for (int j = 0; j < 4; ++j) {
      w[0][j] = *(const bf16x8*)(pb[0] + j * 128 + sub * 8);
      w[1][j] = *(const bf16x8*)(pb[1] + j * 128 + sub * 8);
    }
    #pragma unroll
    for (int h = 0; h < 2; ++h) {
      float s = 0.f;
      #pragma unroll
      for (int j = 0; j < 4; ++j)
        #pragma unroll
        for (int t = 0; t < 8; ++t) { float f = bf2f(w[h][j][t]); s += f * f; }
      #pragma unroll
      for (int off = 1; off < 16; off <<= 1) s += __shfl_xor(s, off);
      const float inv = 1.f / fmaxf(sqrtf(s), 1e-12f);
      if (ok[h]) {
        if (sub == 0) *dst[h] = inv;
        if (do_conv) {
          #pragma unroll
          for (int j = 0; j < 4; ++j) {
            bf16x8 o;
            #pragma unroll
            for (int t = 0; t < 8; ++t) o[t] = f2bf(bf2f(w[h][j][t]) * inv);
            *(bf16x8*)(out[h] + j * 128 + sub * 8) = o;
          }
        }
      }
    }
  }
}

// ---------------- FAST PATH: pure-bf16 NT-GEMM on pre-normalized inputs ----------------
// (round-2 proven version: XCD-grouped mapping + LDS XOR slot-swizzle; 184.5 us)
__global__ __launch_bounds__(256, 3) void arc_gemm_fast(
    const short* __restrict__ A, const short* __restrict__ W,
    const int* __restrict__ labels, const int* __restrict__ flag,
    float* __restrict__ row_sum, float* __restrict__ lablogit) {
  // XCD-aware decode: HW assigns flat bid round-robin (XCD = bid & 7).
  // XCD k owns N-panels with ytile%8==k; its j-th block: ytile=(j>>3)*8+k, xtile=j&7.
  const int bid = blockIdx.x;
  const int k   = bid & 7;
  const int j   = bid >> 3;              // 0..783
  const int ytile = (j >> 3) * 8 + k;    // N-panel
  const int xtile = j & 7;               // M-tile
  if (ytile >= NTILES) return;

  __shared__ short As[BM * BK];     // 8 KB, row-major [row][k], row stride 64 B, slot-swizzled
  __shared__ short Bs[BN * BK];     // 8 KB
  __shared__ int   sh_lab[BM];
  __shared__ float sh_sum[BM][2];

  const int tid  = threadIdx.x;
  const int wave = tid >> 6;
  const int lane = tid & 63;
  const int wy = wave >> 1;         // 2x2 wave grid, each wave 64x64
  const int wx = wave & 1;
  const int lr = lane & 15;
  const int lk = lane >> 4;
  const int mBase = xtile * BM;
  const int nBase = ytile * BN;

  const int srow  = lane >> 2;      // staging: 16 rows per wave-instr
  // physical slot (lane&3) at row srow holds logical slot (lane&3)^((srow>>1)&3);
  // (srow>>1)&3 == (lane>>3)&3
  const int sbyte = (((lane & 3) ^ ((lane >> 3) & 3)) << 4);
  const int rswz  = ((lr >> 1) & 3);   // read-side row swizzle term

  f32x4 zero = {0.f, 0.f, 0.f, 0.f};
  f32x4 acc[4][4];
  #pragma unroll
  for (int i = 0; i < 4; ++i)
    #pragma unroll
    for (int jj = 0; jj < 4; ++jj) acc[i][jj] = zero;

  const char* Ab = (const char*)A;   // bf16 row stride 1024 B
  const char* Wb = (const char*)W;

  for (int kc = 0; kc < KCHUNKS; ++kc) {
    __syncthreads();
    const size_t koff = (size_t)kc * 64 + sbyte;
    #pragma unroll
    for (int it = 0; it < 2; ++it) {
      const int c = wave + it * 4;                  // chunk = 16 rows = 1024 B of LDS
      const int ar = mBase + c * 16 + srow;         // always < 1024
      load16(Ab + (size_t)ar * 1024 + koff, (char*)As + (size_t)c * 1024);
      int br = nBase + c * 16 + srow;
      if (br >= NCLS) br = NCLS - 1;                // clamp; masked in epilogue
      load16(Wb + (size_t)br * 1024 + koff, (char*)Bs + (size_t)c * 1024);
    }
    __syncthreads();                                // drains vmcnt/lgkmcnt before use
    bf16x8 af[4], bfr[4];
    #pragma unroll
    for (int mi = 0; mi < 4; ++mi)
      af[mi] = *(const bf16x8*)(As + ((wy * 64 + mi * 16 + lr) * BK + (lk ^ rswz) * 8));
    #pragma unroll
    for (int ni = 0; ni < 4; ++ni)
      bfr[ni] = *(const bf16x8*)(Bs + ((wx * 64 + ni * 16 + lr) * BK + (lk ^ rswz) * 8));
    #pragma unroll
    for (int mi = 0; mi < 4; ++mi)
      #pragma unroll
      for (int ni = 0; ni < 4; ++ni)
        acc[mi][ni] = MFMA16(af[mi], bfr[ni], acc[mi][ni], 0, 0, 0);
  }

  // ---- epilogue (cos = accumulator directly; inputs pre-normalized) ----
  __syncthreads();
  if (tid < BM) {
    const int r = mBase + tid;
    const int f = *flag;
    sh_lab[tid] = labels[f ? (size_t)(2 * r) : (size_t)r];
  }
  __syncthreads();

  #pragma unroll
  for (int mi = 0; mi < 4; ++mi) {
    #pragma unroll
    for (int reg = 0; reg < 4; ++reg) {
      const int lrow = wy * 64 + mi * 16 + lk * 4 + reg;   // C/D: row=(lane>>4)*4+reg
      const int grow = mBase + lrow;
      const int lab = sh_lab[lrow];
      float s = 0.f;
      #pragma unroll
      for (int ni = 0; ni < 4; ++ni) {
        const int gcol = nBase + wx * 64 + ni * 16 + lr;   // C/D: col=lane&15
        if (gcol < NCLS) {
          const float cosv = acc[mi][ni][reg];
          float logit;
          if (gcol == lab) {
            const float sine = sqrtf(fmaxf(1.f - cosv * cosv, 0.f));
            float phi = cosv * COS_M - sine * SIN_M;
            phi = (cosv > TH_C) ? phi : (cosv - MM_C);
            logit = SCALE_ * phi;
            lablogit[grow] = logit;                        // unique writer grid-wide
          } else {
            logit = SCALE_ * cosv;
          }
          s += __expf(logit - SCALE_);                     // offset-64 softmax partial
        }
      }
      #pragma unroll
      for (int off = 1; off < 16; off <<= 1) s += __shfl_xor(s, off);
      if (lr == 0) sh_sum[lrow][wx] = s;
    }
  }
  __syncthreads();
  if (tid < BM)
    atomicAdd(&row_sum[mBase + tid], sh_sum[tid][0] + sh_sum[tid][1]);
}

// ---------------- FALLBACK: fused NT-GEMM with in-loop dtype staging ----------------
__global__ __launch_bounds__(256, 3) void arc_gemm(
    const void* __restrict__ A, const void* __restrict__ W,
    const float* __restrict__ inv_e, const float* __restrict__ inv_w,
    const int* __restrict__ labels, const int* __restrict__ flag,
    const int* __restrict__ dflag,
    float* __restrict__ row_sum, float* __restrict__ lablogit) {
  __shared__ short As[BM * BK];
  __shared__ short Bs[BN * BK];
  __shared__ int   sh_lab[BM];
  __shared__ float sh_sum[BM][2];

  const int tid  = threadIdx.x;
  const int wave = tid >> 6;
  const int lane = tid & 63;
  const int wy = wave >> 1;
  const int wx = wave & 1;
  const int lr = lane & 15;
  const int lk = lane >> 4;
  const int mBase = blockIdx.x * BM;
  const int nBase = blockIdx.y * BN;
  const int isbf16 = *dflag;

  const int srow  = lane >> 2;
  const int sbyte = (lane & 3) * 16;

  f32x4 zero = {0.f, 0.f, 0.f, 0.f};
  f32x4 acc[4][4];
  #pragma unroll
  for (int i = 0; i < 4; ++i)
    #pragma unroll
    for (int j = 0; j < 4; ++j) acc[i][j] = zero;

  const char*  Ab = (const char*)A;
  const char*  Wb = (const char*)W;
  const float* Af = (const float*)A;
  const float* Wf = (const float*)W;

  for (int kc = 0; kc < KCHUNKS; ++kc) {
    __syncthreads();
    if (isbf16) {
      const size_t koff = (size_t)kc * 64 + sbyte;
      #pragma unroll
      for (int it = 0; it < 2; ++it) {
        const int c = wave + it * 4;
        const int ar = mBase + c * 16 + srow;
        load16(Ab + (size_t)ar * 1024 + koff, (char*)As + (size_t)c * 1024);
        int br = nBase + c * 16 + srow;
        if (br >= NCLS) br = NCLS - 1;
        load16(Wb + (size_t)br * 1024 + koff, (char*)Bs + (size_t)c * 1024);
      }
    } else {
      #pragma unroll
      for (int p = 0; p < 2; ++p) {
        const int u   = p * 256 + tid;
        const int row = u >> 2;
        const int seg = u & 3;
        const float* ga = Af + ((size_t)(mBase + row) * EMB + kc * 32 + seg * 8);
        f32x4 x = *(const f32x4*)ga;
        f32x4 y = *(const f32x4*)(ga + 4);
        bf16x8 tpack;
        #pragma unroll
        for (int j = 0; j < 4; ++j) { tpack[j] = f2bf(x[j]); tpack[j + 4] = f2bf(y[j]); }
        *(bf16x8*)(As + row * BK + seg * 8) = tpack;
        int br = nBase + row;
        if (br >= NCLS) br = NCLS - 1;
        const float* gb = Wf + ((size_t)br * EMB + kc * 32 + seg * 8);
        x = *(const f32x4*)gb;
        y = *(const f32x4*)(gb + 4);
        #pragma unroll
        for (int j = 0; j < 4; ++j) { tpack[j] = f2bf(x[j]); tpack[j + 4] = f2bf(y[j]); }
        *(bf16x8*)(Bs + row * BK + seg * 8) = tpack;
      }
    }
    __syncthreads();
    bf16x8 af[4], bfr[4];
    #pragma unroll
    for (int mi = 0; mi < 4; ++mi)
      af[mi] = *(const bf16x8*)(As + ((wy * 64 + mi * 16 + lr) * BK + lk * 8));
    #pragma unroll
    for (int ni = 0; ni < 4; ++ni)
      bfr[ni] = *(const bf16x8*)(Bs + ((wx * 64 + ni * 16 + lr) * BK + lk * 8));
    #pragma unroll
    for (int mi = 0; mi < 4; ++mi)
      #pragma unroll
      for (int ni = 0; ni < 4; ++ni)
        acc[mi][ni] = MFMA16(af[mi], bfr[ni], acc[mi][ni], 0, 0, 0);
  }

  __syncthreads();
  if (tid < BM) {
    const int r = mBase + tid;
    const int f = *flag;
    sh_lab[tid] = labels[f ? (size_t)(2 * r) : (size_t)r];
  }
  __syncthreads();

  #pragma unroll
  for (int mi = 0; mi < 4; ++mi) {
    #pragma unroll
    for (int reg = 0; reg < 4; ++reg) {
      const int lrow = wy * 64 + mi * 16 + lk * 4 + reg;
      const int grow = mBase + lrow;
      const float ie = inv_e[grow];
      const int lab = sh_lab[lrow];
      float s = 0.f;
      #pragma unroll
      for (int ni = 0; ni < 4; ++ni) {
        const int gcol = nBase + wx * 64 + ni * 16 + lr;
        if (gcol < NCLS) {
          const float cosv = acc[mi][ni][reg] * ie * inv_w[gcol];
          float logit;
          if (gcol == lab) {
            const float sine = sqrtf(fmaxf(1.f - cosv * cosv, 0.f));
            float phi = cosv * COS_M - sine * SIN_M;
            phi = (cosv > TH_C) ? phi : (cosv - MM_C);
            logit = SCALE_ * phi;
            lablogit[grow] = logit;
          } else {
            logit = SCALE_ * cosv;
          }
          s += __expf(logit - SCALE_);
        }
      }
      #pragma unroll
      for (int off = 1; off < 16; off <<= 1) s += __shfl_xor(s, off);
      if (lr == 0) sh_sum[lrow][wx] = s;
    }
  }
  __syncthreads();
  if (tid < BM)
    atomicAdd(&row_sum[mBase + tid], sh_sum[tid][0] + sh_sum[tid][1]);
}

// ---------------- fused per-row loss -> mean (single block) ----------------
__global__ __launch_bounds__(512) void loss_kernel(const float* __restrict__ row_sum,
                                                   const float* __restrict__ lablogit,
                                                   float* __restrict__ out) {
  const int t = threadIdx.x;
  float loss = 0.f;
  #pragma unroll
  for (int i = 0; i < 2; ++i) {
    const int r = t + i * 512;
    loss += SCALE_ + logf(row_sum[r]) - lablogit[r];
  }
  #pragma unroll
  for (int off = 1; off < 64; off <<= 1) loss += __shfl_xor(loss, off);
  __shared__ float rs[8];
  if ((t & 63) == 0) rs[t >> 6] = loss;
  __syncthreads();
  if (t == 0) {
    float s = 0.f;
    #pragma unroll
    for (int i = 0; i < 8; ++i) s += rs[i];
    out[0] = s * (1.0f / 1024.0f);   // reference output is float32
  }
}

// ---------------- launch ----------------
extern "C" void kernel_launch(void* const* d_in, const int* in_sizes, int n_in,
                              void* d_out, int out_size, void* d_ws, size_t ws_size,
                              hipStream_t stream) {
  const void* emb   = d_in[0];          // [1024][512]  bf16 or fp32 (auto-detected)
  const void* wgt   = d_in[1];          // [100000][512]
  const int* labels = (const int*)d_in[2];   // int32 or int64 (auto-detected)
  float* out = (float*)d_out;

  const int NORM_BLOCKS = (B_ROWS + NCLS + 31) / 32;   // 32 rows/block, 2 rows/thread

  // fast-path workspace: pre-normalized bf16 copies of W and A
  const size_t WN_SHORTS = (size_t)NCLS * EMB;        // 51,200,000
  const size_t AN_SHORTS = (size_t)B_ROWS * EMB;      // 524,288
  const size_t FAST_NEED = (WN_SHORTS + AN_SHORTS) * 2 + 103075u * 4;  // ~103.9 MB

  if (ws_size >= FAST_NEED) {
    short* Wn = (short*)d_ws;
    short* An = Wn + WN_SHORTS;
    float* tail     = (float*)(An + AN_SHORTS);
    float* inv_e    = tail;               // 1024 (fallback parity)
    float* inv_w    = tail + 1024;        // 100000
    float* lablogit = tail + 101024;      // 1024
    float* row_sum  = tail + 102048;      // 1024
    float* accum    = tail + 103072;      // 1
    int*   flag     = (int*)(tail + 103073);
    int*   dflag    = (int*)(tail + 103074);

    setup_kernel<<<1, 512, 0, stream>>>(emb, labels, row_sum, accum, flag, dflag);
    normconv_kernel<<<NORM_BLOCKS, 256, 0, stream>>>(
        emb, wgt, dflag, inv_e, inv_w, An, Wn, 1);
    // 8 XCDs x 784 blocks each (ceil(782/8)*8 y-groups x 8 x-tiles); 16 no-op blocks
    arc_gemm_fast<<<8 * 784, 256, 0, stream>>>(An, Wn, labels, flag, row_sum, lablogit);
    loss_kernel<<<1, 512, 0, stream>>>(row_sum, lablogit, out);
  } else {
    float* ws       = (float*)d_ws;
    float* inv_e    = ws;                 // 1024
    float* inv_w    = ws + 1024;          // 100000
    float* lablogit = ws + 101024;        // 1024
    float* row_sum  = ws + 102048;        // 1024
    float* accum    = ws + 103072;        // 1
    int*   flag     = (int*)(ws + 103073);
    int*   dflag    = (int*)(ws + 103074);

    setup_kernel<<<1, 512, 0, stream>>>(emb, labels, row_sum, accum, flag, dflag);
    normconv_kernel<<<NORM_BLOCKS, 256, 0, stream>>>(
        emb, wgt, dflag, inv_e, inv_w, (short*)inv_e, (short*)inv_e, 0);
    dim3 grid(8, NTILES);
    arc_gemm<<<grid, 256, 0, stream>>>(emb, wgt, inv_e, inv_w, labels, flag, dflag, row_sum, lablogit);
    loss_kernel<<<1, 512, 0, stream>>>(row_sum, lablogit, out);
  }
}

// Round 7
// 431.175 us; speedup vs baseline: 1.1178x; 1.0486x over previous
//
#include <hip/hip_runtime.h>
#include <hip/hip_bf16.h>
#include <math.h>

// ---------------- problem constants ----------------
#define B_ROWS 1024
#define EMB    512
#define NCLS   100000
#define SCALE_ 64.0f
// margin = 0.5
#define COS_M 0.8775825618903728f
#define SIN_M 0.479425538604203f
#define TH_C  (-0.8775825618903728f)
#define MM_C  0.2397127693021015f

// ---------------- fallback GEMM tiling (128^2, BK=32) ----------------
#define BM 128
#define BN 128
#define BK 32
#define NTILES 782   // ceil(100000/128)
#define KCHUNKS 16   // 512/32

// ---------------- fast GEMM: same 128^2 structure, BK=64 (half the barriers) ----
#define BK2   64
#define KCH2  8      // 512/64

typedef __attribute__((ext_vector_type(8))) short bf16x8;   // 8 bf16 = 4 VGPRs
typedef __attribute__((ext_vector_type(4))) short s16x4;
typedef __attribute__((ext_vector_type(4))) float f32x4;

typedef __attribute__((address_space(1))) const unsigned int GLP;
typedef __attribute__((address_space(3))) unsigned int LDP;

__device__ __forceinline__ float bf2f(short u) {
  unsigned int x = ((unsigned int)(unsigned short)u) << 16;
  return __builtin_bit_cast(float, x);
}
__device__ __forceinline__ short f2bf(float f) {   // RNE fp32 -> bf16
  unsigned int u = __builtin_bit_cast(unsigned int, f);
  u += 0x7FFF + ((u >> 16) & 1);
  return (short)(u >> 16);
}

// async global->LDS, 16B/lane; LDS dest = wave-uniform base, lane i lands at base + i*16
__device__ __forceinline__ void load16(const void* g, void* l) {
  __builtin_amdgcn_global_load_lds((GLP*)g, (LDP*)l, 16, 0, 0);
}

#define MFMA16 __builtin_amdgcn_mfma_f32_16x16x32_bf16

// ---------------- setup: zero accums, detect label width AND input dtype ----------------
__global__ void setup_kernel(const void* __restrict__ emb, const int* __restrict__ labels,
                             float* __restrict__ row_sum, float* __restrict__ accum,
                             int* __restrict__ flag, int* __restrict__ dflag) {
  const int t = threadIdx.x;           // 512 threads
  row_sum[t] = 0.f;
  row_sum[t + 512] = 0.f;
  if (t == 0) *accum = 0.f;

  // ---- input dtype probe (wave 0): ssq of emb row 0 read AS bf16.
  if (t < 64) {
    bf16x8 v = *(const bf16x8*)((const short*)emb + t * 8);
    float s = 0.f;
    #pragma unroll
    for (int j = 0; j < 8; ++j) { float f = bf2f(v[j]); s += f * f; }
    #pragma unroll
    for (int off = 1; off < 64; off <<= 1) s += __shfl_xor(s, off);
    if (t == 0) *dflag = (s < 1e8f) ? 1 : 0;       // NaN/inf compare false -> fp32
  }

  // ---- label width probe: high words if int64 are all zero
  int v = labels[2 * t + 1];
  #pragma unroll
  for (int off = 1; off < 64; off <<= 1) v |= __shfl_xor(v, off);
  __shared__ int red[8];
  if ((t & 63) == 0) red[t >> 6] = v;
  __syncthreads();
  if (t == 0) {
    int o = 0;
    #pragma unroll
    for (int i = 0; i < 8; ++i) o |= red[i];
    *flag = (o == 0) ? 1 : 0;          // 1 => int64 labels (read low word at 2*r)
  }
}

// ---------------- inverse L2 norms + (optional) normalized-bf16 write-back ----------------
// v4 (proven round 6): 16 lanes/row, 2 rows/thread (16 outstanding loads),
// non-temporal fp32 reads (dead after this pass; keep L3 for the Wn stream).
__global__ __launch_bounds__(256) void normconv_kernel(
    const void* __restrict__ emb, const void* __restrict__ wgt,
    const int* __restrict__ dflag,
    float* __restrict__ inv_e, float* __restrict__ inv_w,
    short* __restrict__ An, short* __restrict__ Wn, const int do_conv) {
  const int sub  = threadIdx.x & 15;       // lane within row-group
  const int rloc = threadIdx.x >> 4;       // 0..15
  const int isbf16 = *dflag;

  const float* pf[2];
  const short* pb[2];
  float* dst[2];
  short* out[2];
  bool   ok[2];
  #pragma unroll
  for (int h = 0; h < 2; ++h) {
    const int row = blockIdx.x * 32 + h * 16 + rloc;
    int r;
    const void* base;
    if (row < B_ROWS) {                      // blocks 0..31 are pure-emb (1024 = 32*32)
      r = row; base = emb; dst[h] = inv_e + row; out[h] = An + (size_t)row * EMB; ok[h] = true;
    } else {
      r = row - B_ROWS;
      ok[h] = (r < NCLS);
      if (r >= NCLS) r = NCLS - 1;           // clamp: safe load, stores guarded
      base = wgt; dst[h] = inv_w + r; out[h] = Wn + (size_t)r * EMB;
    }
    pf[h] = (const float*)base + (size_t)r * EMB;
    pb[h] = (const short*)base + (size_t)r * EMB;
  }

  if (!isbf16) {
    f32x4 v[2][8];
    #pragma unroll
    for (int j = 0; j < 8; ++j) {           // interleave the two rows' streams
      v[0][j] = __builtin_nontemporal_load((const f32x4*)(pf[0] + j * 64 + sub * 4));
      v[1][j] = __builtin_nontemporal_load((const f32x4*)(pf[1] + j * 64 + sub * 4));
    }
    #pragma unroll
    for (int h = 0; h < 2; ++h) {
      float s = 0.f;
      #pragma unroll
      for (int j = 0; j < 8; ++j)
        #pragma unroll
        for (int t = 0; t < 4; ++t) s += v[h][j][t] * v[h][j][t];
      #pragma unroll
      for (int off = 1; off < 16; off <<= 1) s += __shfl_xor(s, off);
      const float inv = 1.f / fmaxf(sqrtf(s), 1e-12f);
      if (ok[h]) {
        if (sub == 0) *dst[h] = inv;
        if (do_conv) {
          #pragma unroll
          for (int j = 0; j < 8; ++j) {
            s16x4 o;
            #pragma unroll
            for (int t = 0; t < 4; ++t) o[t] = f2bf(v[h][j][t] * inv);
            *(s16x4*)(out[h] + j * 64 + sub * 4) = o;
          }
        }
      }
    }
  } else {
    bf16x8 w[2][4];
    #pragma unroll
    for (int j = 0; j < 4; ++j) {
      w[0][j] = *(const bf16x8*)(pb[0] + j * 128 + sub * 8);
      w[1][j] = *(const bf16x8*)(pb[1] + j * 128 + sub * 8);
    }
    #pragma unroll
    for (int h = 0; h < 2; ++h) {
      float s = 0.f;
      #pragma unroll
      for (int j = 0; j < 4; ++j)
        #pragma unroll
        for (int t = 0; t < 8; ++t) { float f = bf2f(w[h][j][t]); s += f * f; }
      #pragma unroll
      for (int off = 1; off < 16; off <<= 1) s += __shfl_xor(s, off);
      const float inv = 1.f / fmaxf(sqrtf(s), 1e-12f);
      if (ok[h]) {
        if (sub == 0) *dst[h] = inv;
        if (do_conv) {
          #pragma unroll
          for (int j = 0; j < 4; ++j) {
            bf16x8 o;
            #pragma unroll
            for (int t = 0; t < 8; ++t) o[t] = f2bf(bf2f(w[h][j][t]) * inv);
            *(bf16x8*)(out[h] + j * 128 + sub * 8) = o;
          }
        }
      }
    }
  }
}

// ---------------- FAST PATH: 128^2 BK=64 NT-GEMM (proven structure, half the barriers) ----
// XCD-grouped mapping (round 2). LDS rows 128 B; XOR swizzle phys_slot = logical ^ (row&7)
// (m201 st_16x32 geometry) via pre-swizzled global source + swizzled ds_read.
__global__ __launch_bounds__(256, 3) void arc_gemm_fast(
    const short* __restrict__ A, const short* __restrict__ W,
    const int* __restrict__ labels, const int* __restrict__ flag,
    float* __restrict__ row_sum, float* __restrict__ lablogit) {
  // XCD-aware decode: HW assigns flat bid round-robin (XCD = bid & 7).
  const int bid = blockIdx.x;
  const int k   = bid & 7;
  const int j   = bid >> 3;              // 0..783
  const int ytile = (j >> 3) * 8 + k;    // N-panel
  const int xtile = j & 7;               // M-tile
  if (ytile >= NTILES) return;

  __shared__ short As[BM * BK2];    // 16 KB, [row][slot] phys, row stride 128 B
  __shared__ short Bs[BN * BK2];    // 16 KB
  __shared__ int   sh_lab[BM];
  __shared__ float sh_sum[BM][2];

  const int tid  = threadIdx.x;
  const int wave = tid >> 6;
  const int lane = tid & 63;
  const int wy = wave >> 1;         // 2x2 wave grid, each wave 64x64
  const int wx = wave & 1;
  const int lr = lane & 15;
  const int lk = lane >> 4;
  const int mBase = xtile * BM;
  const int nBase = ytile * BN;

  // staging: each gload_lds covers 8 rows x 128 B; lane -> row_in=lane>>3, phys=lane&7.
  // instr base rows are multiples of 8, so row&7 == lane>>3; source fetches the
  // logical slot that belongs at phys (lane&7):  sslot = (lane&7) ^ ((lane>>3)&7).
  const int srow8 = lane >> 3;                       // row within 8-row stripe
  const int sslot = (lane & 7) ^ (srow8 & 7);

  f32x4 zero = {0.f, 0.f, 0.f, 0.f};
  f32x4 acc[4][4];
  #pragma unroll
  for (int i = 0; i < 4; ++i)
    #pragma unroll
    for (int jj = 0; jj < 4; ++jj) acc[i][jj] = zero;

  const char* Ab = (const char*)A;   // bf16 row stride 1024 B
  const char* Wb = (const char*)W;

  for (int kc = 0; kc < KCH2; ++kc) {
    __syncthreads();
    const size_t koff = (size_t)kc * 128 + sslot * 16;
    #pragma unroll
    for (int it = 0; it < 4; ++it) {
      const int i = wave + it * 4;                  // stage-instr id 0..15 (8 rows each)
      const int ar = mBase + i * 8 + srow8;         // always < 1024
      load16(Ab + (size_t)ar * 1024 + koff, (char*)As + (size_t)i * 1024);
      int br = nBase + i * 8 + srow8;
      if (br >= NCLS) br = NCLS - 1;                // clamp; masked in epilogue
      load16(Wb + (size_t)br * 1024 + koff, (char*)Bs + (size_t)i * 1024);
    }
    __syncthreads();                                // drains vmcnt/lgkmcnt before use

    bf16x8 af[2][4], bfr[2][4];
    #pragma unroll
    for (int mi = 0; mi < 4; ++mi) {
      const int ra = wy * 64 + mi * 16 + lr;
      af[0][mi] = *(const bf16x8*)(As + ra * BK2 + ((lk       ^ (ra & 7)) * 8));
      af[1][mi] = *(const bf16x8*)(As + ra * BK2 + (((4 | lk) ^ (ra & 7)) * 8));
    }
    #pragma unroll
    for (int ni = 0; ni < 4; ++ni) {
      const int rb = wx * 64 + ni * 16 + lr;
      bfr[0][ni] = *(const bf16x8*)(Bs + rb * BK2 + ((lk       ^ (rb & 7)) * 8));
      bfr[1][ni] = *(const bf16x8*)(Bs + rb * BK2 + (((4 | lk) ^ (rb & 7)) * 8));
    }
    #pragma unroll
    for (int mi = 0; mi < 4; ++mi)
      #pragma unroll
      for (int ni = 0; ni < 4; ++ni) {
        acc[mi][ni] = MFMA16(af[0][mi], bfr[0][ni], acc[mi][ni], 0, 0, 0);
        acc[mi][ni] = MFMA16(af[1][mi], bfr[1][ni], acc[mi][ni], 0, 0, 0);
      }
  }

  // ---- epilogue (cos = accumulator directly; inputs pre-normalized) ----
  __syncthreads();
  if (tid < BM) {
    const int r = mBase + tid;
    const int f = *flag;
    sh_lab[tid] = labels[f ? (size_t)(2 * r) : (size_t)r];
  }
  __syncthreads();

  #pragma unroll
  for (int mi = 0; mi < 4; ++mi) {
    #pragma unroll
    for (int reg = 0; reg < 4; ++reg) {
      const int lrow = wy * 64 + mi * 16 + lk * 4 + reg;   // C/D: row=(lane>>4)*4+reg
      const int grow = mBase + lrow;
      const int lab = sh_lab[lrow];
      float s = 0.f;
      #pragma unroll
      for (int ni = 0; ni < 4; ++ni) {
        const int gcol = nBase + wx * 64 + ni * 16 + lr;   // C/D: col=lane&15
        if (gcol < NCLS) {
          const float cosv = acc[mi][ni][reg];
          float logit;
          if (gcol == lab) {
            const float sine = sqrtf(fmaxf(1.f - cosv * cosv, 0.f));
            float phi = cosv * COS_M - sine * SIN_M;
            phi = (cosv > TH_C) ? phi : (cosv - MM_C);
            logit = SCALE_ * phi;
            lablogit[grow] = logit;                        // unique writer grid-wide
          } else {
            logit = SCALE_ * cosv;
          }
          s += __expf(logit - SCALE_);                     // offset-64 softmax partial
        }
      }
      #pragma unroll
      for (int off = 1; off < 16; off <<= 1) s += __shfl_xor(s, off);
      if (lr == 0) sh_sum[lrow][wx] = s;
    }
  }
  __syncthreads();
  if (tid < BM)
    atomicAdd(&row_sum[mBase + tid], sh_sum[tid][0] + sh_sum[tid][1]);
}

// ---------------- FALLBACK: fused NT-GEMM with in-loop dtype staging (BK=32) ----------------
__global__ __launch_bounds__(256, 3) void arc_gemm(
    const void* __restrict__ A, const void* __restrict__ W,
    const float* __restrict__ inv_e, const float* __restrict__ inv_w,
    const int* __restrict__ labels, const int* __restrict__ flag,
    const int* __restrict__ dflag,
    float* __restrict__ row_sum, float* __restrict__ lablogit) {
  __shared__ short As[BM * BK];
  __shared__ short Bs[BN * BK];
  __shared__ int   sh_lab[BM];
  __shared__ float sh_sum[BM][2];

  const int tid  = threadIdx.x;
  const int wave = tid >> 6;
  const int lane = tid & 63;
  const int wy = wave >> 1;
  const int wx = wave & 1;
  const int lr = lane & 15;
  const int lk = lane >> 4;
  const int mBase = blockIdx.x * BM;
  const int nBase = blockIdx.y * BN;
  const int isbf16 = *dflag;

  const int srow  = lane >> 2;
  const int sbyte = (lane & 3) * 16;

  f32x4 zero = {0.f, 0.f, 0.f, 0.f};
  f32x4 acc[4][4];
  #pragma unroll
  for (int i = 0; i < 4; ++i)
    #pragma unroll
    for (int j = 0; j < 4; ++j) acc[i][j] = zero;

  const char*  Ab = (const char*)A;
  const char*  Wb = (const char*)W;
  const float* Af = (const float*)A;
  const float* Wf = (const float*)W;

  for (int kc = 0; kc < KCHUNKS; ++kc) {
    __syncthreads();
    if (isbf16) {
      const size_t koff = (size_t)kc * 64 + sbyte;
      #pragma unroll
      for (int it = 0; it < 2; ++it) {
        const int c = wave + it * 4;
        const int ar = mBase + c * 16 + srow;
        load16(Ab + (size_t)ar * 1024 + koff, (char*)As + (size_t)c * 1024);
        int br = nBase + c * 16 + srow;
        if (br >= NCLS) br = NCLS - 1;
        load16(Wb + (size_t)br * 1024 + koff, (char*)Bs + (size_t)c * 1024);
      }
    } else {
      #pragma unroll
      for (int p = 0; p < 2; ++p) {
        const int u   = p * 256 + tid;
        const int row = u >> 2;
        const int seg = u & 3;
        const float* ga = Af + ((size_t)(mBase + row) * EMB + kc * 32 + seg * 8);
        f32x4 x = *(const f32x4*)ga;
        f32x4 y = *(const f32x4*)(ga + 4);
        bf16x8 tpack;
        #pragma unroll
        for (int j = 0; j < 4; ++j) { tpack[j] = f2bf(x[j]); tpack[j + 4] = f2bf(y[j]); }
        *(bf16x8*)(As + row * BK + seg * 8) = tpack;
        int br = nBase + row;
        if (br >= NCLS) br = NCLS - 1;
        const float* gb = Wf + ((size_t)br * EMB + kc * 32 + seg * 8);
        x = *(const f32x4*)gb;
        y = *(const f32x4*)(gb + 4);
        #pragma unroll
        for (int j = 0; j < 4; ++j) { tpack[j] = f2bf(x[j]); tpack[j + 4] = f2bf(y[j]); }
        *(bf16x8*)(Bs + row * BK + seg * 8) = tpack;
      }
    }
    __syncthreads();
    bf16x8 af[4], bfr[4];
    #pragma unroll
    for (int mi = 0; mi < 4; ++mi)
      af[mi] = *(const bf16x8*)(As + ((wy * 64 + mi * 16 + lr) * BK + lk * 8));
    #pragma unroll
    for (int ni = 0; ni < 4; ++ni)
      bfr[ni] = *(const bf16x8*)(Bs + ((wx * 64 + ni * 16 + lr) * BK + lk * 8));
    #pragma unroll
    for (int mi = 0; mi < 4; ++mi)
      #pragma unroll
      for (int ni = 0; ni < 4; ++ni)
        acc[mi][ni] = MFMA16(af[mi], bfr[ni], acc[mi][ni], 0, 0, 0);
  }

  __syncthreads();
  if (tid < BM) {
    const int r = mBase + tid;
    const int f = *flag;
    sh_lab[tid] = labels[f ? (size_t)(2 * r) : (size_t)r];
  }
  __syncthreads();

  #pragma unroll
  for (int mi = 0; mi < 4; ++mi) {
    #pragma unroll
    for (int reg = 0; reg < 4; ++reg) {
      const int lrow = wy * 64 + mi * 16 + lk * 4 + reg;
      const int grow = mBase + lrow;
      const float ie = inv_e[grow];
      const int lab = sh_lab[lrow];
      float s = 0.f;
      #pragma unroll
      for (int ni = 0; ni < 4; ++ni) {
        const int gcol = nBase + wx * 64 + ni * 16 + lr;
        if (gcol < NCLS) {
          const float cosv = acc[mi][ni][reg] * ie * inv_w[gcol];
          float logit;
          if (gcol == lab) {
            const float sine = sqrtf(fmaxf(1.f - cosv * cosv, 0.f));
            float phi = cosv * COS_M - sine * SIN_M;
            phi = (cosv > TH_C) ? phi : (cosv - MM_C);
            logit = SCALE_ * phi;
            lablogit[grow] = logit;
          } else {
            logit = SCALE_ * cosv;
          }
          s += __expf(logit - SCALE_);
        }
      }
      #pragma unroll
      for (int off = 1; off < 16; off <<= 1) s += __shfl_xor(s, off);
      if (lr == 0) sh_sum[lrow][wx] = s;
    }
  }
  __syncthreads();
  if (tid < BM)
    atomicAdd(&row_sum[mBase + tid], sh_sum[tid][0] + sh_sum[tid][1]);
}

// ---------------- fused per-row loss -> mean (single block) ----------------
__global__ __launch_bounds__(512) void loss_kernel(const float* __restrict__ row_sum,
                                                   const float* __restrict__ lablogit,
                                                   float* __restrict__ out) {
  const int t = threadIdx.x;
  float loss = 0.f;
  #pragma unroll
  for (int i = 0; i < 2; ++i) {
    const int r = t + i * 512;
    loss += SCALE_ + logf(row_sum[r]) - lablogit[r];
  }
  #pragma unroll
  for (int off = 1; off < 64; off <<= 1) loss += __shfl_xor(loss, off);
  __shared__ float rs[8];
  if ((t & 63) == 0) rs[t >> 6] = loss;
  __syncthreads();
  if (t == 0) {
    float s = 0.f;
    #pragma unroll
    for (int i = 0; i < 8; ++i) s += rs[i];
    out[0] = s * (1.0f / 1024.0f);   // reference output is float32
  }
}

// ---------------- launch ----------------
extern "C" void kernel_launch(void* const* d_in, const int* in_sizes, int n_in,
                              void* d_out, int out_size, void* d_ws, size_t ws_size,
                              hipStream_t stream) {
  const void* emb   = d_in[0];          // [1024][512]  bf16 or fp32 (auto-detected)
  const void* wgt   = d_in[1];          // [100000][512]
  const int* labels = (const int*)d_in[2];   // int32 or int64 (auto-detected)
  float* out = (float*)d_out;

  const int NORM_BLOCKS = (B_ROWS + NCLS + 31) / 32;   // 32 rows/block, 2 rows/thread

  // fast-path workspace: pre-normalized bf16 copies of W and A
  const size_t WN_SHORTS = (size_t)NCLS * EMB;        // 51,200,000
  const size_t AN_SHORTS = (size_t)B_ROWS * EMB;      // 524,288
  const size_t FAST_NEED = (WN_SHORTS + AN_SHORTS) * 2 + 103075u * 4;  // ~103.9 MB

  if (ws_size >= FAST_NEED) {
    short* Wn = (short*)d_ws;
    short* An = Wn + WN_SHORTS;
    float* tail     = (float*)(An + AN_SHORTS);
    float* inv_e    = tail;               // 1024 (fallback parity)
    float* inv_w    = tail + 1024;        // 100000
    float* lablogit = tail + 101024;      // 1024
    float* row_sum  = tail + 102048;      // 1024
    float* accum    = tail + 103072;      // 1
    int*   flag     = (int*)(tail + 103073);
    int*   dflag    = (int*)(tail + 103074);

    setup_kernel<<<1, 512, 0, stream>>>(emb, labels, row_sum, accum, flag, dflag);
    normconv_kernel<<<NORM_BLOCKS, 256, 0, stream>>>(
        emb, wgt, dflag, inv_e, inv_w, An, Wn, 1);
    // 8 XCDs x 784 blocks each (ceil(782/8)*8 y-groups x 8 x-tiles); 16 no-op blocks
    arc_gemm_fast<<<8 * 784, 256, 0, stream>>>(An, Wn, labels, flag, row_sum, lablogit);
    loss_kernel<<<1, 512, 0, stream>>>(row_sum, lablogit, out);
  } else {
    float* ws       = (float*)d_ws;
    float* inv_e    = ws;                 // 1024
    float* inv_w    = ws + 1024;          // 100000
    float* lablogit = ws + 101024;        // 1024
    float* row_sum  = ws + 102048;        // 1024
    float* accum    = ws + 103072;        // 1
    int*   flag     = (int*)(ws + 103073);
    int*   dflag    = (int*)(ws + 103074);

    setup_kernel<<<1, 512, 0, stream>>>(emb, labels, row_sum, accum, flag, dflag);
    normconv_kernel<<<NORM_BLOCKS, 256, 0, stream>>>(
        emb, wgt, dflag, inv_e, inv_w, (short*)inv_e, (short*)inv_e, 0);
    dim3 grid(8, NTILES);
    arc_gemm<<<grid, 256, 0, stream>>>(emb, wgt, inv_e, inv_w, labels, flag, dflag, row_sum, lablogit);
    loss_kernel<<<1, 512, 0, stream>>>(row_sum, lablogit, out);
  }
}